// Round 11
// baseline (2515.956 us; speedup 1.0000x reference)
//
#include <hip/hip_runtime.h>
#include <math.h>

#define MDIM 512
#define NDIM 2048
#define KDIM 2048
#define NLAYERS 20

static const size_t MN = (size_t)MDIM * NDIM;        // 1,048,576
static const size_t OPN = (size_t)KDIM * KDIM;       // 4,194,304

using bf16x8 = __attribute__((ext_vector_type(8))) short;
using f32x4  = __attribute__((ext_vector_type(4))) float;

__device__ __forceinline__ double softplusd(double v) {
    return (v > 20.0) ? v : log1p(exp(v));
}

// ---- fp32 trig prox (R0) — used only as Newton SEED ----
__device__ __forceinline__ float prox_cardan_f(float eta, float x) {
    const float b  = -(1.0f + x);
    const float c  = x - 2.0f * eta;
    const float dd = eta;
    const float p  = c - b * b * (1.0f / 3.0f);
    const float q  = 2.0f * b * b * b * (1.0f / 27.0f) - b * c * (1.0f / 3.0f) + dd;
    const float disc = -4.0f * p * p * p - 27.0f * q * q;
    const float pm = fminf(p, -1e-12f);
    const float mm = 2.0f * sqrtf(-pm * (1.0f / 3.0f));
    float arg = 3.0f * q / (pm * mm);
    arg = fminf(fmaxf(arg, -1.0f), 1.0f);
    const float th = acosf(arg);
    const float TWO_PI = 6.28318530717958647692f;
    const float r0 = mm * cosf(th * (1.0f / 3.0f)) - b * (1.0f / 3.0f);
    const float r1 = mm * cosf((th - TWO_PI) * (1.0f / 3.0f)) - b * (1.0f / 3.0f);
    const float r2 = mm * cosf((th - 2.0f * TWO_PI) * (1.0f / 3.0f)) - b * (1.0f / 3.0f);
    const bool in0 = (r0 > 0.0f) && (r0 < 1.0f);
    const bool in1 = (r1 > 0.0f) && (r1 < 1.0f);
    const bool in2 = (r2 > 0.0f) && (r2 < 1.0f);
    const float root3 = in0 ? r0 : (in1 ? r1 : (in2 ? r2 : r0));
    const float s = sqrtf(fmaxf(q * q * 0.25f + p * p * p * (1.0f / 27.0f), 0.0f));
    const float root1 = cbrtf(-q * 0.5f + s) + cbrtf(-q * 0.5f - s) - b * (1.0f / 3.0f);
    const float u = (disc >= 0.0f) ? root3 : root1;
    return fminf(fmaxf(u, 1e-9f), 1.0f - 1e-9f);
}

// fp64 prox via Newton on P(u)=u(u-1)(u-x)-eta(2u-1): unique root in (0,1).
__device__ __forceinline__ double prox_newton_d(double eta, double x) {
    double u = (double)prox_cardan_f((float)eta, (float)x);
#pragma unroll
    for (int i = 0; i < 4; ++i) {
        const double um1 = u - 1.0;
        const double umx = u - x;
        const double P  = u * um1 * umx - eta * (2.0 * u - 1.0);
        const double dP = um1 * umx + u * umx + u * um1 - 2.0 * eta;
        u = u - P / dP;
        u = fmin(fmax(u, 1e-12), 1.0 - 1e-12);
    }
    return fmin(fmax(u, 1e-9), 1.0 - 1e-9);
}

// ---- bf16 helpers + EXACT fp32 Dekker 3-way split ----
__device__ __forceinline__ unsigned short f2bf(float f) {
    unsigned u = __float_as_uint(f);
    unsigned r = (u + 0x7FFFu + ((u >> 16) & 1u)) >> 16;
    return (unsigned short)r;
}
__device__ __forceinline__ float bf2f(unsigned short h) {
    return __uint_as_float(((unsigned)h) << 16);
}
__device__ __forceinline__ void split3f(float f, unsigned short& b1,
                                        unsigned short& b2, unsigned short& b3) {
    b1 = f2bf(f);
    const float r1 = f - bf2f(b1);
    b2 = f2bf(r1);
    const float r2 = r1 - bf2f(b2);
    b3 = f2bf(r2);
}

// ===========================================================================
// TILED FRAGMENT LAYOUT (R8-proven on A; R13 extends to W): element (r, k)
// of an RxK row-major operand lives at ushort offset
//   ((rsub*(K/32) + kblk)*64 + lane)*8 + e
// rsub=r>>4, kblk=k>>5, lane=((k>>3)&3)*16 + (r&15), e=k&7.
// This is EXACTLY the per-lane 16B fragment a mfma_16x16x32 wave reads, so
// fragment loads are per-lane-contiguous coalesced 1KB streams that advance
// 512 ushorts per K=32 substep. Producers write it; gemm reads it. With
// both A and W tiled, the GEMM needs NO LDS and NO barriers.
// ===========================================================================

// ---------------------------------------------------------------------------
// split3_a: 3-way bf16 split of row-major [512x2048] src into tiled A-planes.
// (R8-verified.) 512 blocks, 8 elements/thread.
// ---------------------------------------------------------------------------
__global__ __launch_bounds__(256) void split3_a(
    const float* __restrict__ src,
    unsigned short* __restrict__ p1, unsigned short* __restrict__ p2,
    unsigned short* __restrict__ p3) {
    const int b = blockIdx.x;
    const int wid = threadIdx.x >> 6, lane = threadIdx.x & 63;
    const int msub = b >> 4, kblk = (b & 15) * 4 + wid;
    const int m = msub * 16 + (lane & 15);
    const int n = kblk * 32 + (lane >> 4) * 8;
    const size_t flat = (size_t)m * NDIM + n;
    const size_t tile = ((size_t)(msub * 64 + kblk) * 64 + lane) * 8;
    const float4 a = *(const float4*)(src + flat);
    const float4 c = *(const float4*)(src + flat + 4);
    const float v[8] = {a.x, a.y, a.z, a.w, c.x, c.y, c.z, c.w};
    unsigned short o1[8], o2[8], o3[8];
#pragma unroll
    for (int j = 0; j < 8; ++j) split3f(v[j], o1[j], o2[j], o3[j]);
    *(ushort4*)(p1 + tile)     = make_ushort4(o1[0], o1[1], o1[2], o1[3]);
    *(ushort4*)(p1 + tile + 4) = make_ushort4(o1[4], o1[5], o1[6], o1[7]);
    *(ushort4*)(p2 + tile)     = make_ushort4(o2[0], o2[1], o2[2], o2[3]);
    *(ushort4*)(p2 + tile + 4) = make_ushort4(o2[4], o2[5], o2[6], o2[7]);
    *(ushort4*)(p3 + tile)     = make_ushort4(o3[0], o3[1], o3[2], o3[3]);
    *(ushort4*)(p3 + tile + 4) = make_ushort4(o3[4], o3[5], o3[6], o3[7]);
}

// ---------------------------------------------------------------------------
// split3_ot: tiled 3-way bf16 split of a [2048x2048] row-major operand
// (s1 + regl*s2, s2 nullable). 2048 blocks, 8 elements/thread.
// CACHED: if cached!=0 and greg[layer]==greg[0], early-exit (W identical).
// ---------------------------------------------------------------------------
__global__ __launch_bounds__(256) void split3_ot(
    const float* __restrict__ s1, const float* __restrict__ s2,
    const float* __restrict__ greg, int layer, int cached,
    unsigned short* __restrict__ p1, unsigned short* __restrict__ p2,
    unsigned short* __restrict__ p3) {
    if (cached && layer > 0 && greg[layer] == greg[0]) return;
    const int b = blockIdx.x;                 // 0..2047
    const int wid = threadIdx.x >> 6, lane = threadIdx.x & 63;
    const int nsub = b >> 4, kblk = (b & 15) * 4 + wid;   // nsub<128, kblk<64
    const int n = nsub * 16 + (lane & 15);
    const int k = kblk * 32 + (lane >> 4) * 8;
    const size_t flat = (size_t)n * KDIM + k;
    const size_t tile = ((size_t)(nsub * 64 + kblk) * 64 + lane) * 8;
    float reglf = 0.0f;
    if (s2) reglf = (float)(softplusd((double)greg[layer]) * 0.01);
    const float4 a = *(const float4*)(s1 + flat);
    const float4 c = *(const float4*)(s1 + flat + 4);
    float4 b2 = make_float4(0.f, 0.f, 0.f, 0.f);
    float4 d2 = make_float4(0.f, 0.f, 0.f, 0.f);
    if (s2) {
        b2 = *(const float4*)(s2 + flat);
        d2 = *(const float4*)(s2 + flat + 4);
    }
    const float va[8] = {a.x, a.y, a.z, a.w, c.x, c.y, c.z, c.w};
    const float vb[8] = {b2.x, b2.y, b2.z, b2.w, d2.x, d2.y, d2.z, d2.w};
    unsigned short o1[8], o2[8], o3[8];
#pragma unroll
    for (int j = 0; j < 8; ++j)
        split3f(fmaf(reglf, vb[j], va[j]), o1[j], o2[j], o3[j]);
    *(ushort4*)(p1 + tile)     = make_ushort4(o1[0], o1[1], o1[2], o1[3]);
    *(ushort4*)(p1 + tile + 4) = make_ushort4(o1[4], o1[5], o1[6], o1[7]);
    *(ushort4*)(p2 + tile)     = make_ushort4(o2[0], o2[1], o2[2], o2[3]);
    *(ushort4*)(p2 + tile + 4) = make_ushort4(o2[4], o2[5], o2[6], o2[7]);
    *(ushort4*)(p3 + tile)     = make_ushort4(o3[0], o3[1], o3[2], o3[3]);
    *(ushort4*)(p3 + tile + 4) = make_ushort4(o3[4], o3[5], o3[6], o3[7]);
}

// ---------------------------------------------------------------------------
// bf16x3 split-K NT GEMM — R13: BOTH operands tiled, pure register
// streaming. NO LDS, NO barriers, NO DMA.
//
// R12 post-mortem: W's LDS machinery (DMA + writes + ds_reads + 16
// barriers/dispatch) pays for dedup that the A side proved unprofitable
// (R12's direct duplicated A reads beat R11's LDS-dedup'd A). R13 applies
// the same tiled fragment layout to W: 12 coalesced per-lane streams
// (6 A + 6 W), 2-deep register prefetch, MFMA. R7's failure (row-major
// fragment loads shattered coalescing) is fixed by the layout; R8's
// failure (wave-private LDS staging) is deleted. XCD chunk keeps each
// XCD's W slice at 3MB (L2-fit); duplicated reads (waves sharing wm/wn)
// hit L1/L2.
//
// Numerics BIT-IDENTICAL to the 2606us baseline: same fragment values
// (layout remap only), same per-accumulator 6-product MFMA chain, same K
// order, same epilogue. S=2 fixed.
// ---------------------------------------------------------------------------
__global__ __launch_bounds__(256, 2) void gemm_bf16x3(
    const unsigned short* __restrict__ A1, const unsigned short* __restrict__ A2,
    const unsigned short* __restrict__ A3,
    const unsigned short* __restrict__ W1, const unsigned short* __restrict__ W2,
    const unsigned short* __restrict__ W3,
    float* __restrict__ Part, int klen, int S) {
    const int tid = threadIdx.x;

    // ---- XCD-chunked bijective block swizzle (nwg = 256*S, divisible by 8)
    const int nwg = 256 * S;
    const int cpx = nwg >> 3;
    const int bid = blockIdx.x;
    const int g   = (bid & 7) * cpx + (bid >> 3);
    const int xs  = g / (8 * S);              // N-tile 0..31 (4 per XCD)
    const int rr  = g - xs * (8 * S);
    const int ys  = rr & 7;                   // M-tile (fastest: shares W)
    const int zs  = rr >> 3;                  // K-slice
    const int n0 = xs * 64;
    const int m0 = ys * 64;

    const int lane = tid & 63, wid = tid >> 6;
    const int quad = lane >> 4, lrow = lane & 15;
    const int wm = (wid >> 1) * 32, wn = (wid & 1) * 32;

    const int nsteps = klen >> 5;             // 32 at S=2 (even)
    const int kblk0  = zs * nsteps;

    // fragment stream bases (advance 512 ushorts per K=32 substep)
    const unsigned short* pA[2][3];
    const unsigned short* pW[2][3];
#pragma unroll
    for (int t = 0; t < 2; ++t) {
        const int msub = ys * 4 + (wid >> 1) * 2 + t;
        const int nsub = xs * 4 + (wid & 1) * 2 + t;
        const size_t ab = ((size_t)(msub * 64 + kblk0) * 64 + lane) * 8;
        const size_t wb = ((size_t)(nsub * 64 + kblk0) * 64 + lane) * 8;
        pA[t][0] = A1 + ab; pA[t][1] = A2 + ab; pA[t][2] = A3 + ab;
        pW[t][0] = W1 + wb; pW[t][1] = W2 + wb; pW[t][2] = W3 + wb;
    }

    f32x4 ahi[2][2], alo[2][2];
#pragma unroll
    for (int a = 0; a < 2; ++a)
#pragma unroll
        for (int b2 = 0; b2 < 2; ++b2) {
            ahi[a][b2] = (f32x4){0.f, 0.f, 0.f, 0.f};
            alo[a][b2] = (f32x4){0.f, 0.f, 0.f, 0.f};
        }

    auto LOAD = [&](bf16x8 (&fa)[2][3], bf16x8 (&fw)[2][3], int s) {
        const size_t off = (size_t)s * 512;
#pragma unroll
        for (int t = 0; t < 2; ++t)
#pragma unroll
            for (int p = 0; p < 3; ++p) {
                fa[t][p] = *(const bf16x8*)(pA[t][p] + off);
                fw[t][p] = *(const bf16x8*)(pW[t][p] + off);
            }
    };
    auto MF = [&](bf16x8 (&fa)[2][3], bf16x8 (&fw)[2][3]) {
        __builtin_amdgcn_s_setprio(1);
#pragma unroll
        for (int tm = 0; tm < 2; ++tm)
#pragma unroll
            for (int tn = 0; tn < 2; ++tn) {
                ahi[tm][tn] = __builtin_amdgcn_mfma_f32_16x16x32_bf16(fa[tm][0], fw[tn][0], ahi[tm][tn], 0, 0, 0);
                alo[tm][tn] = __builtin_amdgcn_mfma_f32_16x16x32_bf16(fa[tm][0], fw[tn][1], alo[tm][tn], 0, 0, 0);
                alo[tm][tn] = __builtin_amdgcn_mfma_f32_16x16x32_bf16(fa[tm][1], fw[tn][0], alo[tm][tn], 0, 0, 0);
                alo[tm][tn] = __builtin_amdgcn_mfma_f32_16x16x32_bf16(fa[tm][1], fw[tn][1], alo[tm][tn], 0, 0, 0);
                alo[tm][tn] = __builtin_amdgcn_mfma_f32_16x16x32_bf16(fa[tm][0], fw[tn][2], alo[tm][tn], 0, 0, 0);
                alo[tm][tn] = __builtin_amdgcn_mfma_f32_16x16x32_bf16(fa[tm][2], fw[tn][0], alo[tm][tn], 0, 0, 0);
            }
        __builtin_amdgcn_s_setprio(0);
    };

    // 2-deep register prefetch, named buffers (static indexing only)
    bf16x8 faA[2][3], fwA[2][3], faB[2][3], fwB[2][3];
    LOAD(faA, fwA, 0);
    for (int s = 0; s < nsteps; s += 2) {
        if (s + 1 < nsteps) LOAD(faB, fwB, s + 1);
        MF(faA, fwA);
        if (s + 2 < nsteps) LOAD(faA, fwA, s + 2);
        if (s + 1 < nsteps) MF(faB, fwB);
    }

    float* P = Part + (size_t)zs * MN;
#pragma unroll
    for (int tm = 0; tm < 2; ++tm)
#pragma unroll
        for (int tn = 0; tn < 2; ++tn) {
            const int mbase = m0 + wm + tm * 16 + quad * 4;
            const int nn = n0 + wn + tn * 16 + lrow;
#pragma unroll
            for (int r2 = 0; r2 < 4; ++r2)
                P[(size_t)(mbase + r2) * NDIM + nn] = ahi[tm][tn][r2] + alo[tm][tn][r2];
        }
}

// ---------------------------------------------------------------------------
// combine3 (R8-verified remap): fp64 sum of fp32 split-K partials + epilogue
// + fp32-exact 3-way bf16 split written in the TILED A layout. Per-element
// arithmetic identical to baseline. MODE 2 stores row-major fp32 state/out.
// 512 blocks, 8 elements/thread.
// ---------------------------------------------------------------------------
template <int MODE>
__global__ __launch_bounds__(256) void combine3(
    const float* __restrict__ Part, int S,
    const float* __restrict__ Xc, const float* __restrict__ Xb,
    float* __restrict__ stateOut,
    unsigned short* __restrict__ p1, unsigned short* __restrict__ p2,
    unsigned short* __restrict__ p3,
    const float* __restrict__ gam, const float* __restrict__ gmu,
    const float* __restrict__ greg, int layer) {
    const int b = blockIdx.x;
    const int wid = threadIdx.x >> 6, lane = threadIdx.x & 63;
    const int msub = b >> 4, kblk = (b & 15) * 4 + wid;
    const int m = msub * 16 + (lane & 15);
    const int n = kblk * 32 + (lane >> 4) * 8;
    const size_t flat = (size_t)m * NDIM + n;
    const size_t tile = ((size_t)(msub * 64 + kblk) * 64 + lane) * 8;

    double s[8] = {0., 0., 0., 0., 0., 0., 0., 0.};
    for (int z = 0; z < S; ++z) {
        const float4 a = *(const float4*)(Part + (size_t)z * MN + flat);
        const float4 c = *(const float4*)(Part + (size_t)z * MN + flat + 4);
        s[0] += (double)a.x; s[1] += (double)a.y; s[2] += (double)a.z; s[3] += (double)a.w;
        s[4] += (double)c.x; s[5] += (double)c.y; s[6] += (double)c.z; s[7] += (double)c.w;
    }
    float v[8];
    if (MODE == 0) {
        const double g = softplusd((double)gam[layer]);
        const float4 xa = *(const float4*)(Xc + flat);
        const float4 xc = *(const float4*)(Xc + flat + 4);
        const float4 ba = *(const float4*)(Xb + flat);
        const float4 bc = *(const float4*)(Xb + flat + 4);
        const float xcv[8] = {xa.x, xa.y, xa.z, xa.w, xc.x, xc.y, xc.z, xc.w};
        const float xbv[8] = {ba.x, ba.y, ba.z, ba.w, bc.x, bc.y, bc.z, bc.w};
#pragma unroll
        for (int j = 0; j < 8; ++j)
            v[j] = (float)((double)xcv[j] - g * (s[j] - (double)xbv[j]));
    } else if (MODE == 1) {
        const double g   = softplusd((double)gam[layer]);
        const double eta = g * softplusd((double)gmu[layer]) * 1e-6;
#pragma unroll
        for (int j = 0; j < 8; ++j)
            v[j] = (float)prox_newton_d(eta, s[j]);
    } else {
#pragma unroll
        for (int j = 0; j < 8; ++j) v[j] = (float)s[j];
        *(float4*)(stateOut + flat)     = make_float4(v[0], v[1], v[2], v[3]);
        *(float4*)(stateOut + flat + 4) = make_float4(v[4], v[5], v[6], v[7]);
    }
    unsigned short o1[8], o2[8], o3[8];
#pragma unroll
    for (int j = 0; j < 8; ++j) split3f(v[j], o1[j], o2[j], o3[j]);
    *(ushort4*)(p1 + tile)     = make_ushort4(o1[0], o1[1], o1[2], o1[3]);
    *(ushort4*)(p1 + tile + 4) = make_ushort4(o1[4], o1[5], o1[6], o1[7]);
    *(ushort4*)(p2 + tile)     = make_ushort4(o2[0], o2[1], o2[2], o2[3]);
    *(ushort4*)(p2 + tile + 4) = make_ushort4(o2[4], o2[5], o2[6], o2[7]);
    *(ushort4*)(p3 + tile)     = make_ushort4(o3[0], o3[1], o3[2], o3[3]);
    *(ushort4*)(p3 + tile + 4) = make_ushort4(o3[4], o3[5], o3[6], o3[7]);
}

// ===========================================================================
// Legacy R2 fallback (fp32 vector FMA + fp64 drain), used only for tiny ws.
// ===========================================================================
#define BM 64
#define BN 64
#define BK 32
#define LDSP 68

__device__ __forceinline__ double prox_cardan_d(double eta, double x) {
    const double b  = -(1.0 + x);
    const double c  = x - 2.0 * eta;
    const double dd = eta;
    const double p  = c - b * b * (1.0 / 3.0);
    const double q  = 2.0 * b * b * b * (1.0 / 27.0) - b * c * (1.0 / 3.0) + dd;
    const double disc = -4.0 * p * p * p - 27.0 * q * q;
    const double pm = fmin(p, -1e-12);
    const double mm = 2.0 * sqrt(-pm * (1.0 / 3.0));
    double arg = 3.0 * q / (pm * mm);
    arg = fmin(fmax(arg, -1.0), 1.0);
    const double th = acos(arg);
    const double TWO_PI = 6.283185307179586476925286766559;
    const double r0 = mm * cos(th * (1.0 / 3.0)) - b * (1.0 / 3.0);
    const double r1 = mm * cos((th - TWO_PI) * (1.0 / 3.0)) - b * (1.0 / 3.0);
    const double r2 = mm * cos((th - 2.0 * TWO_PI) * (1.0 / 3.0)) - b * (1.0 / 3.0);
    const bool in0 = (r0 > 0.0) && (r0 < 1.0);
    const bool in1 = (r1 > 0.0) && (r1 < 1.0);
    const bool in2 = (r2 > 0.0) && (r2 < 1.0);
    const double root3 = in0 ? r0 : (in1 ? r1 : (in2 ? r2 : r0));
    const double s = sqrt(fmax(q * q * 0.25 + p * p * p * (1.0 / 27.0), 0.0));
    const double root1 = cbrt(-q * 0.5 + s) + cbrt(-q * 0.5 - s) - b * (1.0 / 3.0);
    const double u = (disc >= 0.0) ? root3 : root1;
    return fmin(fmax(u, 1e-9), 1.0 - 1e-9);
}

template <bool FUSE2>
__global__ __launch_bounds__(256, 4) void gemm_nt_splitk(
    const float* __restrict__ A, const float* __restrict__ W1,
    const float* __restrict__ W2, double* __restrict__ Part,
    const float* __restrict__ greg, int layer, int klen) {
    __shared__ float As[BK][LDSP];
    __shared__ float Ws[BK][LDSP];
    const int tid = threadIdx.x;
    const int m0 = blockIdx.y * BM;
    const int n0 = blockIdx.x * BN;
    const int kbase = blockIdx.z * klen;
    float reglf = 0.0f;
    if (FUSE2) reglf = (float)(softplusd((double)greg[layer]) * 0.01);
    const int lrow = tid >> 3;
    const int lkc  = (tid & 7) << 2;
    const float* pA  = A  + (size_t)(m0 + lrow) * KDIM + kbase + lkc;
    const float* pW  = W1 + (size_t)(n0 + lrow) * KDIM + kbase + lkc;
    const float* pW2 = FUSE2 ? (W2 + (size_t)(n0 + lrow) * KDIM + kbase + lkc) : nullptr;
    float4 ra[2], rw[2];
    ra[0] = *(const float4*)(pA);
    ra[1] = *(const float4*)(pA + 32 * KDIM);
    rw[0] = *(const float4*)(pW);
    rw[1] = *(const float4*)(pW + 32 * KDIM);
    if (FUSE2) {
        const float4 u0 = *(const float4*)(pW2);
        const float4 u1 = *(const float4*)(pW2 + 32 * KDIM);
        rw[0].x += reglf * u0.x; rw[0].y += reglf * u0.y;
        rw[0].z += reglf * u0.z; rw[0].w += reglf * u0.w;
        rw[1].x += reglf * u1.x; rw[1].y += reglf * u1.y;
        rw[1].z += reglf * u1.z; rw[1].w += reglf * u1.w;
    }
    float  acc[4][4]   = {};
    double acc64[4][4] = {};
    const int tx = (tid & 15) << 2;
    const int ty = (tid >> 4) << 2;
    int it = 0;
    for (int k0 = 0; k0 < klen; k0 += BK, ++it) {
#pragma unroll
        for (int h = 0; h < 2; ++h) {
            const int row = lrow + (h << 5);
            As[lkc + 0][row] = (h ? ra[1].x : ra[0].x);
            As[lkc + 1][row] = (h ? ra[1].y : ra[0].y);
            As[lkc + 2][row] = (h ? ra[1].z : ra[0].z);
            As[lkc + 3][row] = (h ? ra[1].w : ra[0].w);
            Ws[lkc + 0][row] = (h ? rw[1].x : rw[0].x);
            Ws[lkc + 1][row] = (h ? rw[1].y : rw[0].y);
            Ws[lkc + 2][row] = (h ? rw[1].z : rw[0].z);
            Ws[lkc + 3][row] = (h ? rw[1].w : rw[0].w);
        }
        __syncthreads();
        if (k0 + BK < klen) {
            const float* qA = pA + k0 + BK;
            ra[0] = *(const float4*)(qA);
            ra[1] = *(const float4*)(qA + 32 * KDIM);
            const float* qW = pW + k0 + BK;
            rw[0] = *(const float4*)(qW);
            rw[1] = *(const float4*)(qW + 32 * KDIM);
            if (FUSE2) {
                const float* qW2 = pW2 + k0 + BK;
                const float4 u0 = *(const float4*)(qW2);
                const float4 u1 = *(const float4*)(qW2 + 32 * KDIM);
                rw[0].x += reglf * u0.x; rw[0].y += reglf * u0.y;
                rw[0].z += reglf * u0.z; rw[0].w += reglf * u0.w;
                rw[1].x += reglf * u1.x; rw[1].y += reglf * u1.y;
                rw[1].z += reglf * u1.z; rw[1].w += reglf * u1.w;
            }
        }
#pragma unroll
        for (int kk = 0; kk < BK; ++kk) {
            const float4 a4 = *(const float4*)(&As[kk][ty]);
            const float4 b4 = *(const float4*)(&Ws[kk][tx]);
            const float av[4] = {a4.x, a4.y, a4.z, a4.w};
            const float bv[4] = {b4.x, b4.y, b4.z, b4.w};
#pragma unroll
            for (int r = 0; r < 4; ++r)
#pragma unroll
                for (int cc = 0; cc < 4; ++cc)
                    acc[r][cc] = fmaf(av[r], bv[cc], acc[r][cc]);
        }
        __syncthreads();
        if ((it & 1) == 1) {
#pragma unroll
            for (int r = 0; r < 4; ++r)
#pragma unroll
                for (int cc = 0; cc < 4; ++cc) {
                    acc64[r][cc] += (double)acc[r][cc];
                    acc[r][cc] = 0.0f;
                }
        }
    }
#pragma unroll
    for (int r = 0; r < 4; ++r)
#pragma unroll
        for (int cc = 0; cc < 4; ++cc)
            acc64[r][cc] += (double)acc[r][cc];
    double* Pz = Part + (size_t)blockIdx.z * MN;
#pragma unroll
    for (int r = 0; r < 4; ++r) {
        double* q = Pz + (size_t)(m0 + ty + r) * NDIM + n0 + tx;
        *(double2*)(q)     = make_double2(acc64[r][0], acc64[r][1]);
        *(double2*)(q + 2) = make_double2(acc64[r][2], acc64[r][3]);
    }
}

template <int MODE>
__global__ __launch_bounds__(256) void combine_ep(
    const double* __restrict__ Part, int nslices,
    const float* __restrict__ Xc, const float* __restrict__ Xb,
    float* __restrict__ Out,
    const float* __restrict__ gam, const float* __restrict__ gmu,
    const float* __restrict__ greg, int layer) {
    const size_t i4 = ((size_t)blockIdx.x * 256 + threadIdx.x) * 4;
    double s0 = 0.0, s1 = 0.0, s2 = 0.0, s3 = 0.0;
    for (int z = 0; z < nslices; ++z) {
        const double* p = Part + (size_t)z * MN + i4;
        const double2 a = *(const double2*)(p);
        const double2 b = *(const double2*)(p + 2);
        s0 += a.x; s1 += a.y; s2 += b.x; s3 += b.y;
    }
    float4 o;
    if (MODE == 0) {
        const double g = softplusd((double)gam[layer]);
        const float4 xc = *(const float4*)(Xc + i4);
        const float4 xb = *(const float4*)(Xb + i4);
        o.x = (float)((double)xc.x - g * (s0 - (double)xb.x));
        o.y = (float)((double)xc.y - g * (s1 - (double)xb.y));
        o.z = (float)((double)xc.z - g * (s2 - (double)xb.z));
        o.w = (float)((double)xc.w - g * (s3 - (double)xb.w));
    } else if (MODE == 1) {
        const double g   = softplusd((double)gam[layer]);
        const double eta = g * softplusd((double)gmu[layer]) * 1e-6;
        o.x = (float)prox_cardan_d(eta, s0);
        o.y = (float)prox_cardan_d(eta, s1);
        o.z = (float)prox_cardan_d(eta, s2);
        o.w = (float)prox_cardan_d(eta, s3);
    } else {
        o.x = (float)s0; o.y = (float)s1; o.z = (float)s2; o.w = (float)s3;
    }
    *(float4*)(Out + i4) = o;
}

// ===========================================================================
extern "C" void kernel_launch(void* const* d_in, const int* in_sizes, int n_in,
                              void* d_out, int out_size, void* d_ws, size_t ws_size,
                              hipStream_t stream) {
    const float* x    = (const float*)d_in[0];
    const float* x_b  = (const float*)d_in[1];
    const float* tDD  = (const float*)d_in[2];
    const float* tTT  = (const float*)d_in[3];
    const float* Peig = (const float*)d_in[4];
    const float* Pelt = (const float*)d_in[5];
    const float* gam  = (const float*)d_in[6];
    const float* gmu  = (const float*)d_in[7];
    const float* greg = (const float*)d_in[8];
    float* out = (float*)d_out;

    const size_t TRI_OP_B = 3 * OPN * 2;                 // 25,165,824
    const size_t TRI_A_B  = 3 * MN * 2;                  // 6,291,456
    const size_t STATE_B  = MN * 4;                      // 4,194,304
    // S=2 partials: full = 3 triples, mid = shared triple
    const size_t full_need = 3 * TRI_OP_B + 2 * TRI_A_B + STATE_B + 2 * MN * 4; // 100,663,296
    const size_t mid_need  = 1 * TRI_OP_B + 2 * TRI_A_B + STATE_B + 2 * MN * 4; //  50,331,648

    const bool full = (ws_size >= full_need);
    const bool mid  = (!full && ws_size >= mid_need);

    if (full || mid) {
        const int S = 2;                                 // FIXED (bit-identity)
        const int klen = KDIM / S;
        char* p = (char*)d_ws;
        unsigned short *Wt1, *Wt2, *Wt3, *Pe1, *Pe2, *Pe3, *Pg1, *Pg2, *Pg3;
        if (full) {
            Wt1 = (unsigned short*)p;        Wt2 = Wt1 + OPN; Wt3 = Wt2 + OPN; p += TRI_OP_B;
            Pe1 = (unsigned short*)p;        Pe2 = Pe1 + OPN; Pe3 = Pe2 + OPN; p += TRI_OP_B;
            Pg1 = (unsigned short*)p;        Pg2 = Pg1 + OPN; Pg3 = Pg2 + OPN; p += TRI_OP_B;
        } else {
            Wt1 = (unsigned short*)p;        Wt2 = Wt1 + OPN; Wt3 = Wt2 + OPN; p += TRI_OP_B;
            Pe1 = Wt1; Pe2 = Wt2; Pe3 = Wt3;
            Pg1 = Wt1; Pg2 = Wt2; Pg3 = Wt3;
        }
        unsigned short* Aa1 = (unsigned short*)p; unsigned short* Aa2 = Aa1 + MN;
        unsigned short* Aa3 = Aa2 + MN; p += TRI_A_B;
        unsigned short* Ab1 = (unsigned short*)p; unsigned short* Ab2 = Ab1 + MN;
        unsigned short* Ab3 = Ab2 + MN; p += TRI_A_B;
        float* state = (float*)p; p += STATE_B;
        float* part  = (float*)p;

        const dim3 gg((unsigned)(256 * S));              // 512 WGs, swizzled
        const unsigned agrid = 512;                      // tiled A / combine
        const unsigned tgrid = 2048;                     // tiled 2048^2 split

        split3_a<<<agrid, 256, 0, stream>>>(x, Aa1, Aa2, Aa3);
        if (full) {
            split3_ot<<<tgrid, 256, 0, stream>>>(Pelt, nullptr, greg, 0, 0, Pe1, Pe2, Pe3);
            split3_ot<<<tgrid, 256, 0, stream>>>(Peig, nullptr, greg, 0, 0, Pg1, Pg2, Pg3);
        }

        unsigned short *c1 = Aa1, *c2 = Aa2, *c3 = Aa3;
        unsigned short *d1 = Ab1, *d2 = Ab2, *d3 = Ab3;

        for (int l = 0; l < NLAYERS; ++l) {
            // W split (tiled); cached early-exit in full mode
            split3_ot<<<tgrid, 256, 0, stream>>>(tTT, tDD, greg, l, (full ? 1 : 0),
                                                 Wt1, Wt2, Wt3);
            gemm_bf16x3<<<gg, 256, 0, stream>>>(c1, c2, c3, Wt1, Wt2, Wt3, part, klen, S);
            combine3<0><<<agrid, 256, 0, stream>>>(part, S, (l == 0 ? x : state), x_b,
                                                   nullptr, d1, d2, d3, gam, gmu, greg, l);
            if (mid) split3_ot<<<tgrid, 256, 0, stream>>>(Pelt, nullptr, greg, 0, 0, Pe1, Pe2, Pe3);
            gemm_bf16x3<<<gg, 256, 0, stream>>>(d1, d2, d3, Pe1, Pe2, Pe3, part, klen, S);
            combine3<1><<<agrid, 256, 0, stream>>>(part, S, nullptr, nullptr,
                                                   nullptr, c1, c2, c3, gam, gmu, greg, l);
            if (mid) split3_ot<<<tgrid, 256, 0, stream>>>(Peig, nullptr, greg, 0, 0, Pg1, Pg2, Pg3);
            gemm_bf16x3<<<gg, 256, 0, stream>>>(c1, c2, c3, Pg1, Pg2, Pg3, part, klen, S);
            combine3<2><<<agrid, 256, 0, stream>>>(part, S, nullptr, nullptr,
                                                   (l == NLAYERS - 1 ? out : state),
                                                   d1, d2, d3, gam, gmu, greg, l);
            unsigned short* t;
            t = c1; c1 = d1; d1 = t;
            t = c2; c2 = d2; d2 = t;
            t = c3; c3 = d3; d3 = t;
        }
        return;
    }

    // ---------------- legacy R2 fallback (ws < 48 MB) ----------------
    char* wsb = (char*)d_ws;
    float* b0 = (float*)wsb;
    float* b1 = b0 + MN;
    float* b2 = b1 + MN;
    float* b3 = b2 + MN;
    const size_t base_bytes = 4 * MN * sizeof(float);
    double* partd = (double*)(wsb + base_bytes);
    int S = 0;
    if (ws_size >= base_bytes + 2 * MN * sizeof(double)) S = 2;
    else if (ws_size >= base_bytes + 1 * MN * sizeof(double)) S = 1;
    if (S == 0) return;
    const int klen = KDIM / S;
    dim3 gg(NDIM / BN, MDIM / BM, S);
    dim3 cg((unsigned)(MN / 4 / 256));
    const float* cur = x;
    float* bx = b0; float* bu = b1; float* bn = b2; float* bo = b3;
    for (int l = 0; l < NLAYERS; ++l) {
        gemm_nt_splitk<true><<<gg, 256, 0, stream>>>(cur, tTT, tDD, partd, greg, l, klen);
        combine_ep<0><<<cg, 256, 0, stream>>>(partd, S, cur, x_b, bx, gam, gmu, greg, l);
        gemm_nt_splitk<false><<<gg, 256, 0, stream>>>(bx, Pelt, nullptr, partd, greg, l, klen);
        combine_ep<1><<<cg, 256, 0, stream>>>(partd, S, nullptr, nullptr, bu, gam, gmu, greg, l);
        gemm_nt_splitk<false><<<gg, 256, 0, stream>>>(bu, Peig, nullptr, partd, greg, l, klen);
        float* dst = (l == NLAYERS - 1) ? out : bn;
        combine_ep<2><<<cg, 256, 0, stream>>>(partd, S, nullptr, nullptr, dst, gam, gmu, greg, l);
        cur = bn;
        float* t = bn; bn = bo; bo = t;
    }
}

// Round 12
// 2291.141 us; speedup vs baseline: 1.0981x; 1.0981x over previous
//
#include <hip/hip_runtime.h>
#include <math.h>

#define MDIM 512
#define NDIM 2048
#define KDIM 2048
#define NLAYERS 20

static const size_t MN = (size_t)MDIM * NDIM;        // 1,048,576
static const size_t OPN = (size_t)KDIM * KDIM;       // 4,194,304

using bf16x8 = __attribute__((ext_vector_type(8))) short;
using f32x4  = __attribute__((ext_vector_type(4))) float;

__device__ __forceinline__ double softplusd(double v) {
    return (v > 20.0) ? v : log1p(exp(v));
}

// ---- fp32 trig prox (R0) — used only as Newton SEED ----
__device__ __forceinline__ float prox_cardan_f(float eta, float x) {
    const float b  = -(1.0f + x);
    const float c  = x - 2.0f * eta;
    const float dd = eta;
    const float p  = c - b * b * (1.0f / 3.0f);
    const float q  = 2.0f * b * b * b * (1.0f / 27.0f) - b * c * (1.0f / 3.0f) + dd;
    const float disc = -4.0f * p * p * p - 27.0f * q * q;
    const float pm = fminf(p, -1e-12f);
    const float mm = 2.0f * sqrtf(-pm * (1.0f / 3.0f));
    float arg = 3.0f * q / (pm * mm);
    arg = fminf(fmaxf(arg, -1.0f), 1.0f);
    const float th = acosf(arg);
    const float TWO_PI = 6.28318530717958647692f;
    const float r0 = mm * cosf(th * (1.0f / 3.0f)) - b * (1.0f / 3.0f);
    const float r1 = mm * cosf((th - TWO_PI) * (1.0f / 3.0f)) - b * (1.0f / 3.0f);
    const float r2 = mm * cosf((th - 2.0f * TWO_PI) * (1.0f / 3.0f)) - b * (1.0f / 3.0f);
    const bool in0 = (r0 > 0.0f) && (r0 < 1.0f);
    const bool in1 = (r1 > 0.0f) && (r1 < 1.0f);
    const bool in2 = (r2 > 0.0f) && (r2 < 1.0f);
    const float root3 = in0 ? r0 : (in1 ? r1 : (in2 ? r2 : r0));
    const float s = sqrtf(fmaxf(q * q * 0.25f + p * p * p * (1.0f / 27.0f), 0.0f));
    const float root1 = cbrtf(-q * 0.5f + s) + cbrtf(-q * 0.5f - s) - b * (1.0f / 3.0f);
    const float u = (disc >= 0.0f) ? root3 : root1;
    return fminf(fmaxf(u, 1e-9f), 1.0f - 1e-9f);
}

// fp64 prox via Newton on P(u)=u(u-1)(u-x)-eta(2u-1): unique root in (0,1).
__device__ __forceinline__ double prox_newton_d(double eta, double x) {
    double u = (double)prox_cardan_f((float)eta, (float)x);
#pragma unroll
    for (int i = 0; i < 4; ++i) {
        const double um1 = u - 1.0;
        const double umx = u - x;
        const double P  = u * um1 * umx - eta * (2.0 * u - 1.0);
        const double dP = um1 * umx + u * umx + u * um1 - 2.0 * eta;
        u = u - P / dP;
        u = fmin(fmax(u, 1e-12), 1.0 - 1e-12);
    }
    return fmin(fmax(u, 1e-9), 1.0 - 1e-9);
}

// ---- bf16 helpers + EXACT fp32 Dekker 3-way split ----
__device__ __forceinline__ unsigned short f2bf(float f) {
    unsigned u = __float_as_uint(f);
    unsigned r = (u + 0x7FFFu + ((u >> 16) & 1u)) >> 16;
    return (unsigned short)r;
}
__device__ __forceinline__ float bf2f(unsigned short h) {
    return __uint_as_float(((unsigned)h) << 16);
}
__device__ __forceinline__ void split3f(float f, unsigned short& b1,
                                        unsigned short& b2, unsigned short& b3) {
    b1 = f2bf(f);
    const float r1 = f - bf2f(b1);
    b2 = f2bf(r1);
    const float r2 = r1 - bf2f(b2);
    b3 = f2bf(r2);
}

// async 16B global -> LDS DMA (gfx950). LDS dest = wave-uniform base +
// lane*16; swizzling is applied to the per-lane GLOBAL source address.
__device__ __forceinline__ void gl16(const void* g, void* l) {
    __builtin_amdgcn_global_load_lds(
        (const __attribute__((address_space(1))) unsigned int*)g,
        (__attribute__((address_space(3))) unsigned int*)l, 16, 0, 0);
}

// ===========================================================================
// TILED A-PLANE LAYOUT (R8/R12-proven): A element (m, k) at ushort offset
//   ((msub*64 + kblk)*64 + lane)*8 + e
// msub=m>>4, kblk=k>>5, lane=((k>>3)&3)*16 + (m&15), e=k&7.
// Exactly the per-lane 16B fragment a mfma_16x16x32 wave reads -> coalesced
// per-lane-contiguous 1KB streams. Producers (split3_a / combine3) write it.
// W planes stay row-major (R13 proved tiling W regresses: duplicated L2
// traffic beats the LDS machinery it would replace — keep W in LDS).
// ===========================================================================

// ---------------------------------------------------------------------------
// split3_op: row-major 3-way bf16 split of (s1 + regl*s2) — W planes only.
// ---------------------------------------------------------------------------
__global__ __launch_bounds__(256) void split3_op(
    const float* __restrict__ s1, const float* __restrict__ s2,
    const float* __restrict__ greg, int layer,
    unsigned short* __restrict__ p1, unsigned short* __restrict__ p2,
    unsigned short* __restrict__ p3) {
    const size_t i = ((size_t)blockIdx.x * 256 + threadIdx.x) * 4;
    float reglf = 0.0f;
    if (s2) reglf = (float)(softplusd((double)greg[layer]) * 0.01);
    const float4 a = *(const float4*)(s1 + i);
    float4 b = make_float4(0.f, 0.f, 0.f, 0.f);
    if (s2) b = *(const float4*)(s2 + i);
    ushort4 o1, o2, o3;
    split3f(fmaf(reglf, b.x, a.x), o1.x, o2.x, o3.x);
    split3f(fmaf(reglf, b.y, a.y), o1.y, o2.y, o3.y);
    split3f(fmaf(reglf, b.z, a.z), o1.z, o2.z, o3.z);
    split3f(fmaf(reglf, b.w, a.w), o1.w, o2.w, o3.w);
    *(ushort4*)(p1 + i) = o1;
    *(ushort4*)(p2 + i) = o2;
    *(ushort4*)(p3 + i) = o3;
}

// W-split with layer-0 cache: early-exit when greg[layer]==greg[0].
__global__ __launch_bounds__(256) void split3_w(
    const float* __restrict__ s1, const float* __restrict__ s2,
    const float* __restrict__ greg, int layer,
    unsigned short* __restrict__ p1, unsigned short* __restrict__ p2,
    unsigned short* __restrict__ p3) {
    if (layer > 0 && greg[layer] == greg[0]) return;
    const size_t i = ((size_t)blockIdx.x * 256 + threadIdx.x) * 4;
    const float reglf = (float)(softplusd((double)greg[layer]) * 0.01);
    const float4 a = *(const float4*)(s1 + i);
    const float4 b = *(const float4*)(s2 + i);
    ushort4 o1, o2, o3;
    split3f(fmaf(reglf, b.x, a.x), o1.x, o2.x, o3.x);
    split3f(fmaf(reglf, b.y, a.y), o1.y, o2.y, o3.y);
    split3f(fmaf(reglf, b.z, a.z), o1.z, o2.z, o3.z);
    split3f(fmaf(reglf, b.w, a.w), o1.w, o2.w, o3.w);
    *(ushort4*)(p1 + i) = o1;
    *(ushort4*)(p2 + i) = o2;
    *(ushort4*)(p3 + i) = o3;
}

// ---------------------------------------------------------------------------
// split3_a: 3-way bf16 split of row-major src into TILED A-planes (layer 0).
// (R8-verified.) 512 blocks, 8 elements/thread.
// ---------------------------------------------------------------------------
__global__ __launch_bounds__(256) void split3_a(
    const float* __restrict__ src,
    unsigned short* __restrict__ p1, unsigned short* __restrict__ p2,
    unsigned short* __restrict__ p3) {
    const int b = blockIdx.x;
    const int wid = threadIdx.x >> 6, lane = threadIdx.x & 63;
    const int msub = b >> 4, kblk = (b & 15) * 4 + wid;
    const int m = msub * 16 + (lane & 15);
    const int n = kblk * 32 + (lane >> 4) * 8;
    const size_t flat = (size_t)m * NDIM + n;
    const size_t tile = ((size_t)(msub * 64 + kblk) * 64 + lane) * 8;
    const float4 a = *(const float4*)(src + flat);
    const float4 c = *(const float4*)(src + flat + 4);
    const float v[8] = {a.x, a.y, a.z, a.w, c.x, c.y, c.z, c.w};
    unsigned short o1[8], o2[8], o3[8];
#pragma unroll
    for (int j = 0; j < 8; ++j) split3f(v[j], o1[j], o2[j], o3[j]);
    *(ushort4*)(p1 + tile)     = make_ushort4(o1[0], o1[1], o1[2], o1[3]);
    *(ushort4*)(p1 + tile + 4) = make_ushort4(o1[4], o1[5], o1[6], o1[7]);
    *(ushort4*)(p2 + tile)     = make_ushort4(o2[0], o2[1], o2[2], o2[3]);
    *(ushort4*)(p2 + tile + 4) = make_ushort4(o2[4], o2[5], o2[6], o2[7]);
    *(ushort4*)(p3 + tile)     = make_ushort4(o3[0], o3[1], o3[2], o3[3]);
    *(ushort4*)(p3 + tile + 4) = make_ushort4(o3[4], o3[5], o3[6], o3[7]);
}

// ---------------------------------------------------------------------------
// bf16x3 split-K NT GEMM — R14: R12 (best, 2330us) + W-fragment hoist.
//
// R12 structure: tiled-A register streams (no A in LDS), 3-deep circular
// DMA'd W LDS (72KB, pre-swizzled source -> conflict-free reads), ONE
// barrier per refill. R14 tweak: all 12 W fragment ds_reads of a refill
// (both K-substeps) issue as one burst before the MFMA blocks, interleaved
// with the A global-loads — the second read burst no longer sits on the
// critical path between MFMA blocks. (+48 VGPR, fine at 2 waves/SIMD.)
//
// Numerics BIT-IDENTICAL to the 2606us baseline: same fragment values,
// same per-accumulator 6-product MFMA chain, same K order, same epilogue.
// ---------------------------------------------------------------------------
__global__ __launch_bounds__(256, 2) void gemm_bf16x3(
    const unsigned short* __restrict__ A1, const unsigned short* __restrict__ A2,
    const unsigned short* __restrict__ A3,
    const unsigned short* __restrict__ W1, const unsigned short* __restrict__ W2,
    const unsigned short* __restrict__ W3,
    float* __restrict__ Part, int klen, int S) {
    __shared__ __align__(16) unsigned short Wb[3][3][64][64];   // 72KB

    const int tid = threadIdx.x;

    // ---- XCD-chunked bijective block swizzle (nwg = 256*S, divisible by 8)
    const int nwg = 256 * S;
    const int cpx = nwg >> 3;
    const int bid = blockIdx.x;
    const int g   = (bid & 7) * cpx + (bid >> 3);
    const int xs  = g / (8 * S);              // N-tile 0..31 (4 per XCD)
    const int rr  = g - xs * (8 * S);
    const int ys  = rr & 7;                   // M-tile (fastest: shares W)
    const int zs  = rr >> 3;                  // K-slice
    const int n0 = xs * 64;
    const int m0 = ys * 64;
    const int kb = zs * klen;

    const int lane = tid & 63, wid = tid >> 6;
    const int quad = lane >> 4, lrow = lane & 15;
    const int wm = (wid >> 1) * 32, wn = (wid & 1) * 32;
    const int rswz = lrow & 7;                // fragment read swizzle key

    // W DMA source (pre-swizzled col so linear LDS dest == swizzled layout):
    // dest linear idx l = h*256 + tid -> row = h*32 + (tid>>3), phys granule
    // g' = tid&7. Logical granule = g' ^ (row&7) = (tid&7)^((tid>>3)&7).
    const int wrowt = tid >> 3;               // 0..31 (h adds 32)
    const int wgc   = ((tid & 7) ^ (wrowt & 7)) * 8;
    const unsigned short* gWp[3];
    gWp[0] = W1 + (size_t)(n0 + wrowt) * KDIM + kb + wgc;
    gWp[1] = W2 + (size_t)(n0 + wrowt) * KDIM + kb + wgc;
    gWp[2] = W3 + (size_t)(n0 + wrowt) * KDIM + kb + wgc;

    // A tiled fragment-stream bases (advance 512 ushorts per K=32 substep)
    const int nsteps = klen >> 5;             // 32 at S=2
    const int kblk0  = zs * nsteps;
    const unsigned short* pA[2][3];
#pragma unroll
    for (int t = 0; t < 2; ++t) {
        const int msub = ys * 4 + (wid >> 1) * 2 + t;
        const size_t base = ((size_t)(msub * 64 + kblk0) * 64 + lane) * 8;
        pA[t][0] = A1 + base; pA[t][1] = A2 + base; pA[t][2] = A3 + base;
    }

    f32x4 ahi[2][2], alo[2][2];
#pragma unroll
    for (int a = 0; a < 2; ++a)
#pragma unroll
        for (int b2 = 0; b2 < 2; ++b2) {
            ahi[a][b2] = (f32x4){0.f, 0.f, 0.f, 0.f};
            alo[a][b2] = (f32x4){0.f, 0.f, 0.f, 0.f};
        }

    bf16x8 faA[2][3], faB[2][3];

    auto loadA = [&](bf16x8 (&fa)[2][3], int s) {
#pragma unroll
        for (int t = 0; t < 2; ++t)
#pragma unroll
            for (int p = 0; p < 3; ++p)
                fa[t][p] = *(const bf16x8*)(pA[t][p] + (size_t)s * 512);
    };
    auto stageW = [&](int buf, int r1) {
        const int ko = r1 * 64;
#pragma unroll
        for (int p = 0; p < 3; ++p)
#pragma unroll
            for (int h = 0; h < 2; ++h)
                gl16(gWp[p] + (size_t)h * 32 * KDIM + ko,
                     &Wb[buf][p][0][0] + ((size_t)h * 256 + tid) * 8);
    };
    auto MF = [&](bf16x8 (&fa)[2][3], bf16x8 (&fw)[2][3]) {
        __builtin_amdgcn_s_setprio(1);
#pragma unroll
        for (int tm = 0; tm < 2; ++tm)
#pragma unroll
            for (int tn = 0; tn < 2; ++tn) {
                ahi[tm][tn] = __builtin_amdgcn_mfma_f32_16x16x32_bf16(fa[tm][0], fw[tn][0], ahi[tm][tn], 0, 0, 0);
                alo[tm][tn] = __builtin_amdgcn_mfma_f32_16x16x32_bf16(fa[tm][0], fw[tn][1], alo[tm][tn], 0, 0, 0);
                alo[tm][tn] = __builtin_amdgcn_mfma_f32_16x16x32_bf16(fa[tm][1], fw[tn][0], alo[tm][tn], 0, 0, 0);
                alo[tm][tn] = __builtin_amdgcn_mfma_f32_16x16x32_bf16(fa[tm][1], fw[tn][1], alo[tm][tn], 0, 0, 0);
                alo[tm][tn] = __builtin_amdgcn_mfma_f32_16x16x32_bf16(fa[tm][0], fw[tn][2], alo[tm][tn], 0, 0, 0);
                alo[tm][tn] = __builtin_amdgcn_mfma_f32_16x16x32_bf16(fa[tm][2], fw[tn][0], alo[tm][tn], 0, 0, 0);
            }
        __builtin_amdgcn_s_setprio(0);
    };

    const int nref = klen >> 6;               // 16 at S=2

    // prologue: W(0)->buf0, W(1)->buf1, A(substep 0)
    stageW(0, 0);
    stageW(1, 1);
    __builtin_amdgcn_sched_barrier(0);
    loadA(faA, 0);

    for (int r = 0; r < nref; ++r) {
        // publish W(r): insurance drain (steady-state no-op; the A-use wait
        // in the previous refill already drained W(r)) + barrier.
        asm volatile("s_waitcnt vmcnt(12)" ::: "memory");
        __builtin_amdgcn_s_barrier();
        __builtin_amdgcn_sched_barrier(0);

        if (r + 2 < nref) stageW((r + 2) % 3, r + 2);
        __builtin_amdgcn_sched_barrier(0);

        const int buf = r % 3;
        const int s0 = 2 * r;

        // R14: hoist ALL 12 W fragment reads (both substeps) into one burst,
        // interleaved with the A global-loads for the next substeps.
        bf16x8 fw0[2][3], fw1[2][3];
#pragma unroll
        for (int t = 0; t < 2; ++t) {
            const int rww = wn + t * 16 + lrow;
            const int gp0 = ((quad ^ rswz) * 8);
            const int gp1 = (((4 + quad) ^ rswz) * 8);
            fw0[t][0] = *(const bf16x8*)&Wb[buf][0][rww][gp0];
            fw0[t][1] = *(const bf16x8*)&Wb[buf][1][rww][gp0];
            fw0[t][2] = *(const bf16x8*)&Wb[buf][2][rww][gp0];
            fw1[t][0] = *(const bf16x8*)&Wb[buf][0][rww][gp1];
            fw1[t][1] = *(const bf16x8*)&Wb[buf][1][rww][gp1];
            fw1[t][2] = *(const bf16x8*)&Wb[buf][2][rww][gp1];
        }
        if (s0 + 1 < nsteps) loadA(faB, s0 + 1);
        MF(faA, fw0);
        if (s0 + 2 < nsteps) loadA(faA, s0 + 2);
        MF(faB, fw1);
    }

    float* P = Part + (size_t)zs * MN;
#pragma unroll
    for (int tm = 0; tm < 2; ++tm)
#pragma unroll
        for (int tn = 0; tn < 2; ++tn) {
            const int mbase = m0 + wm + tm * 16 + quad * 4;
            const int nn = n0 + wn + tn * 16 + lrow;
#pragma unroll
            for (int r2 = 0; r2 < 4; ++r2)
                P[(size_t)(mbase + r2) * NDIM + nn] = ahi[tm][tn][r2] + alo[tm][tn][r2];
        }
}

// ---------------------------------------------------------------------------
// combine3 (R8-verified remap): fp64 sum of fp32 split-K partials + epilogue
// + fp32-exact 3-way bf16 split written in the TILED A layout. Per-element
// arithmetic identical to baseline. MODE 2 stores row-major fp32 state/out.
// 512 blocks, 8 elements/thread.
// ---------------------------------------------------------------------------
template <int MODE>
__global__ __launch_bounds__(256) void combine3(
    const float* __restrict__ Part, int S,
    const float* __restrict__ Xc, const float* __restrict__ Xb,
    float* __restrict__ stateOut,
    unsigned short* __restrict__ p1, unsigned short* __restrict__ p2,
    unsigned short* __restrict__ p3,
    const float* __restrict__ gam, const float* __restrict__ gmu,
    const float* __restrict__ greg, int layer) {
    const int b = blockIdx.x;
    const int wid = threadIdx.x >> 6, lane = threadIdx.x & 63;
    const int msub = b >> 4, kblk = (b & 15) * 4 + wid;
    const int m = msub * 16 + (lane & 15);
    const int n = kblk * 32 + (lane >> 4) * 8;
    const size_t flat = (size_t)m * NDIM + n;
    const size_t tile = ((size_t)(msub * 64 + kblk) * 64 + lane) * 8;

    double s[8] = {0., 0., 0., 0., 0., 0., 0., 0.};
    for (int z = 0; z < S; ++z) {
        const float4 a = *(const float4*)(Part + (size_t)z * MN + flat);
        const float4 c = *(const float4*)(Part + (size_t)z * MN + flat + 4);
        s[0] += (double)a.x; s[1] += (double)a.y; s[2] += (double)a.z; s[3] += (double)a.w;
        s[4] += (double)c.x; s[5] += (double)c.y; s[6] += (double)c.z; s[7] += (double)c.w;
    }
    float v[8];
    if (MODE == 0) {
        const double g = softplusd((double)gam[layer]);
        const float4 xa = *(const float4*)(Xc + flat);
        const float4 xc = *(const float4*)(Xc + flat + 4);
        const float4 ba = *(const float4*)(Xb + flat);
        const float4 bc = *(const float4*)(Xb + flat + 4);
        const float xcv[8] = {xa.x, xa.y, xa.z, xa.w, xc.x, xc.y, xc.z, xc.w};
        const float xbv[8] = {ba.x, ba.y, ba.z, ba.w, bc.x, bc.y, bc.z, bc.w};
#pragma unroll
        for (int j = 0; j < 8; ++j)
            v[j] = (float)((double)xcv[j] - g * (s[j] - (double)xbv[j]));
    } else if (MODE == 1) {
        const double g   = softplusd((double)gam[layer]);
        const double eta = g * softplusd((double)gmu[layer]) * 1e-6;
#pragma unroll
        for (int j = 0; j < 8; ++j)
            v[j] = (float)prox_newton_d(eta, s[j]);
    } else {
#pragma unroll
        for (int j = 0; j < 8; ++j) v[j] = (float)s[j];
        *(float4*)(stateOut + flat)     = make_float4(v[0], v[1], v[2], v[3]);
        *(float4*)(stateOut + flat + 4) = make_float4(v[4], v[5], v[6], v[7]);
    }
    unsigned short o1[8], o2[8], o3[8];
#pragma unroll
    for (int j = 0; j < 8; ++j) split3f(v[j], o1[j], o2[j], o3[j]);
    *(ushort4*)(p1 + tile)     = make_ushort4(o1[0], o1[1], o1[2], o1[3]);
    *(ushort4*)(p1 + tile + 4) = make_ushort4(o1[4], o1[5], o1[6], o1[7]);
    *(ushort4*)(p2 + tile)     = make_ushort4(o2[0], o2[1], o2[2], o2[3]);
    *(ushort4*)(p2 + tile + 4) = make_ushort4(o2[4], o2[5], o2[6], o2[7]);
    *(ushort4*)(p3 + tile)     = make_ushort4(o3[0], o3[1], o3[2], o3[3]);
    *(ushort4*)(p3 + tile + 4) = make_ushort4(o3[4], o3[5], o3[6], o3[7]);
}

// ===========================================================================
// Legacy R2 fallback (fp32 vector FMA + fp64 drain), used only for tiny ws.
// ===========================================================================
#define BM 64
#define BN 64
#define BK 32
#define LDSP 68

__device__ __forceinline__ double prox_cardan_d(double eta, double x) {
    const double b  = -(1.0 + x);
    const double c  = x - 2.0 * eta;
    const double dd = eta;
    const double p  = c - b * b * (1.0 / 3.0);
    const double q  = 2.0 * b * b * b * (1.0 / 27.0) - b * c * (1.0 / 3.0) + dd;
    const double disc = -4.0 * p * p * p - 27.0 * q * q;
    const double pm = fmin(p, -1e-12);
    const double mm = 2.0 * sqrt(-pm * (1.0 / 3.0));
    double arg = 3.0 * q / (pm * mm);
    arg = fmin(fmax(arg, -1.0), 1.0);
    const double th = acos(arg);
    const double TWO_PI = 6.283185307179586476925286766559;
    const double r0 = mm * cos(th * (1.0 / 3.0)) - b * (1.0 / 3.0);
    const double r1 = mm * cos((th - TWO_PI) * (1.0 / 3.0)) - b * (1.0 / 3.0);
    const double r2 = mm * cos((th - 2.0 * TWO_PI) * (1.0 / 3.0)) - b * (1.0 / 3.0);
    const bool in0 = (r0 > 0.0) && (r0 < 1.0);
    const bool in1 = (r1 > 0.0) && (r1 < 1.0);
    const bool in2 = (r2 > 0.0) && (r2 < 1.0);
    const double root3 = in0 ? r0 : (in1 ? r1 : (in2 ? r2 : r0));
    const double s = sqrt(fmax(q * q * 0.25 + p * p * p * (1.0 / 27.0), 0.0));
    const double root1 = cbrt(-q * 0.5 + s) + cbrt(-q * 0.5 - s) - b * (1.0 / 3.0);
    const double u = (disc >= 0.0) ? root3 : root1;
    return fmin(fmax(u, 1e-9), 1.0 - 1e-9);
}

template <bool FUSE2>
__global__ __launch_bounds__(256, 4) void gemm_nt_splitk(
    const float* __restrict__ A, const float* __restrict__ W1,
    const float* __restrict__ W2, double* __restrict__ Part,
    const float* __restrict__ greg, int layer, int klen) {
    __shared__ float As[BK][LDSP];
    __shared__ float Ws[BK][LDSP];
    const int tid = threadIdx.x;
    const int m0 = blockIdx.y * BM;
    const int n0 = blockIdx.x * BN;
    const int kbase = blockIdx.z * klen;
    float reglf = 0.0f;
    if (FUSE2) reglf = (float)(softplusd((double)greg[layer]) * 0.01);
    const int lrow = tid >> 3;
    const int lkc  = (tid & 7) << 2;
    const float* pA  = A  + (size_t)(m0 + lrow) * KDIM + kbase + lkc;
    const float* pW  = W1 + (size_t)(n0 + lrow) * KDIM + kbase + lkc;
    const float* pW2 = FUSE2 ? (W2 + (size_t)(n0 + lrow) * KDIM + kbase + lkc) : nullptr;
    float4 ra[2], rw[2];
    ra[0] = *(const float4*)(pA);
    ra[1] = *(const float4*)(pA + 32 * KDIM);
    rw[0] = *(const float4*)(pW);
    rw[1] = *(const float4*)(pW + 32 * KDIM);
    if (FUSE2) {
        const float4 u0 = *(const float4*)(pW2);
        const float4 u1 = *(const float4*)(pW2 + 32 * KDIM);
        rw[0].x += reglf * u0.x; rw[0].y += reglf * u0.y;
        rw[0].z += reglf * u0.z; rw[0].w += reglf * u0.w;
        rw[1].x += reglf * u1.x; rw[1].y += reglf * u1.y;
        rw[1].z += reglf * u1.z; rw[1].w += reglf * u1.w;
    }
    float  acc[4][4]   = {};
    double acc64[4][4] = {};
    const int tx = (tid & 15) << 2;
    const int ty = (tid >> 4) << 2;
    int it = 0;
    for (int k0 = 0; k0 < klen; k0 += BK, ++it) {
#pragma unroll
        for (int h = 0; h < 2; ++h) {
            const int row = lrow + (h << 5);
            As[lkc + 0][row] = (h ? ra[1].x : ra[0].x);
            As[lkc + 1][row] = (h ? ra[1].y : ra[0].y);
            As[lkc + 2][row] = (h ? ra[1].z : ra[0].z);
            As[lkc + 3][row] = (h ? ra[1].w : ra[0].w);
            Ws[lkc + 0][row] = (h ? rw[1].x : rw[0].x);
            Ws[lkc + 1][row] = (h ? rw[1].y : rw[0].y);
            Ws[lkc + 2][row] = (h ? rw[1].z : rw[0].z);
            Ws[lkc + 3][row] = (h ? rw[1].w : rw[0].w);
        }
        __syncthreads();
        if (k0 + BK < klen) {
            const float* qA = pA + k0 + BK;
            ra[0] = *(const float4*)(qA);
            ra[1] = *(const float4*)(qA + 32 * KDIM);
            const float* qW = pW + k0 + BK;
            rw[0] = *(const float4*)(qW);
            rw[1] = *(const float4*)(qW + 32 * KDIM);
            if (FUSE2) {
                const float* qW2 = pW2 + k0 + BK;
                const float4 u0 = *(const float4*)(qW2);
                const float4 u1 = *(const float4*)(qW2 + 32 * KDIM);
                rw[0].x += reglf * u0.x; rw[0].y += reglf * u0.y;
                rw[0].z += reglf * u0.z; rw[0].w += reglf * u0.w;
                rw[1].x += reglf * u1.x; rw[1].y += reglf * u1.y;
                rw[1].z += reglf * u1.z; rw[1].w += reglf * u1.w;
            }
        }
#pragma unroll
        for (int kk = 0; kk < BK; ++kk) {
            const float4 a4 = *(const float4*)(&As[kk][ty]);
            const float4 b4 = *(const float4*)(&Ws[kk][tx]);
            const float av[4] = {a4.x, a4.y, a4.z, a4.w};
            const float bv[4] = {b4.x, b4.y, b4.z, b4.w};
#pragma unroll
            for (int r = 0; r < 4; ++r)
#pragma unroll
                for (int cc = 0; cc < 4; ++cc)
                    acc[r][cc] = fmaf(av[r], bv[cc], acc[r][cc]);
        }
        __syncthreads();
        if ((it & 1) == 1) {
#pragma unroll
            for (int r = 0; r < 4; ++r)
#pragma unroll
                for (int cc = 0; cc < 4; ++cc) {
                    acc64[r][cc] += (double)acc[r][cc];
                    acc[r][cc] = 0.0f;
                }
        }
    }
#pragma unroll
    for (int r = 0; r < 4; ++r)
#pragma unroll
        for (int cc = 0; cc < 4; ++cc)
            acc64[r][cc] += (double)acc[r][cc];
    double* Pz = Part + (size_t)blockIdx.z * MN;
#pragma unroll
    for (int r = 0; r < 4; ++r) {
        double* q = Pz + (size_t)(m0 + ty + r) * NDIM + n0 + tx;
        *(double2*)(q)     = make_double2(acc64[r][0], acc64[r][1]);
        *(double2*)(q + 2) = make_double2(acc64[r][2], acc64[r][3]);
    }
}

template <int MODE>
__global__ __launch_bounds__(256) void combine_ep(
    const double* __restrict__ Part, int nslices,
    const float* __restrict__ Xc, const float* __restrict__ Xb,
    float* __restrict__ Out,
    const float* __restrict__ gam, const float* __restrict__ gmu,
    const float* __restrict__ greg, int layer) {
    const size_t i4 = ((size_t)blockIdx.x * 256 + threadIdx.x) * 4;
    double s0 = 0.0, s1 = 0.0, s2 = 0.0, s3 = 0.0;
    for (int z = 0; z < nslices; ++z) {
        const double* p = Part + (size_t)z * MN + i4;
        const double2 a = *(const double2*)(p);
        const double2 b = *(const double2*)(p + 2);
        s0 += a.x; s1 += a.y; s2 += b.x; s3 += b.y;
    }
    float4 o;
    if (MODE == 0) {
        const double g = softplusd((double)gam[layer]);
        const float4 xc = *(const float4*)(Xc + i4);
        const float4 xb = *(const float4*)(Xb + i4);
        o.x = (float)((double)xc.x - g * (s0 - (double)xb.x));
        o.y = (float)((double)xc.y - g * (s1 - (double)xb.y));
        o.z = (float)((double)xc.z - g * (s2 - (double)xb.z));
        o.w = (float)((double)xc.w - g * (s3 - (double)xb.w));
    } else if (MODE == 1) {
        const double g   = softplusd((double)gam[layer]);
        const double eta = g * softplusd((double)gmu[layer]) * 1e-6;
        o.x = (float)prox_cardan_d(eta, s0);
        o.y = (float)prox_cardan_d(eta, s1);
        o.z = (float)prox_cardan_d(eta, s2);
        o.w = (float)prox_cardan_d(eta, s3);
    } else {
        o.x = (float)s0; o.y = (float)s1; o.z = (float)s2; o.w = (float)s3;
    }
    *(float4*)(Out + i4) = o;
}

// ===========================================================================
extern "C" void kernel_launch(void* const* d_in, const int* in_sizes, int n_in,
                              void* d_out, int out_size, void* d_ws, size_t ws_size,
                              hipStream_t stream) {
    const float* x    = (const float*)d_in[0];
    const float* x_b  = (const float*)d_in[1];
    const float* tDD  = (const float*)d_in[2];
    const float* tTT  = (const float*)d_in[3];
    const float* Peig = (const float*)d_in[4];
    const float* Pelt = (const float*)d_in[5];
    const float* gam  = (const float*)d_in[6];
    const float* gmu  = (const float*)d_in[7];
    const float* greg = (const float*)d_in[8];
    float* out = (float*)d_out;

    const size_t TRI_OP_B = 3 * OPN * 2;                 // 25,165,824
    const size_t TRI_A_B  = 3 * MN * 2;                  // 6,291,456
    const size_t STATE_B  = MN * 4;                      // 4,194,304
    // S=2 partials: full = 3 triples, mid = shared triple
    const size_t full_need = 3 * TRI_OP_B + 2 * TRI_A_B + STATE_B + 2 * MN * 4; // 100,663,296
    const size_t mid_need  = 1 * TRI_OP_B + 2 * TRI_A_B + STATE_B + 2 * MN * 4; //  50,331,648

    const bool full = (ws_size >= full_need);
    const bool mid  = (!full && ws_size >= mid_need);

    if (full || mid) {
        const int S = 2;                                 // FIXED (bit-identity)
        const int klen = KDIM / S;
        char* p = (char*)d_ws;
        unsigned short *Wt1, *Wt2, *Wt3, *Pe1, *Pe2, *Pe3, *Pg1, *Pg2, *Pg3;
        if (full) {
            Wt1 = (unsigned short*)p;        Wt2 = Wt1 + OPN; Wt3 = Wt2 + OPN; p += TRI_OP_B;
            Pe1 = (unsigned short*)p;        Pe2 = Pe1 + OPN; Pe3 = Pe2 + OPN; p += TRI_OP_B;
            Pg1 = (unsigned short*)p;        Pg2 = Pg1 + OPN; Pg3 = Pg2 + OPN; p += TRI_OP_B;
        } else {
            Wt1 = (unsigned short*)p;        Wt2 = Wt1 + OPN; Wt3 = Wt2 + OPN; p += TRI_OP_B;
            Pe1 = Wt1; Pe2 = Wt2; Pe3 = Wt3;
            Pg1 = Wt1; Pg2 = Wt2; Pg3 = Wt3;
        }
        unsigned short* Aa1 = (unsigned short*)p; unsigned short* Aa2 = Aa1 + MN;
        unsigned short* Aa3 = Aa2 + MN; p += TRI_A_B;
        unsigned short* Ab1 = (unsigned short*)p; unsigned short* Ab2 = Ab1 + MN;
        unsigned short* Ab3 = Ab2 + MN; p += TRI_A_B;
        float* state = (float*)p; p += STATE_B;
        float* part  = (float*)p;

        const dim3 gg((unsigned)(256 * S));              // 512 WGs, swizzled
        const unsigned agrid = 512;                      // tiled A / combine
        const unsigned ogrid = (unsigned)(OPN / 4 / 256);// 4096

        split3_a<<<agrid, 256, 0, stream>>>(x, Aa1, Aa2, Aa3);
        if (full) {
            split3_op<<<ogrid, 256, 0, stream>>>(Pelt, nullptr, greg, 0, Pe1, Pe2, Pe3);
            split3_op<<<ogrid, 256, 0, stream>>>(Peig, nullptr, greg, 0, Pg1, Pg2, Pg3);
        }

        unsigned short *c1 = Aa1, *c2 = Aa2, *c3 = Aa3;
        unsigned short *d1 = Ab1, *d2 = Ab2, *d3 = Ab3;

        for (int l = 0; l < NLAYERS; ++l) {
            if (full) {
                // cached: early-exits when greg[l]==greg[0] (W identical)
                split3_w<<<ogrid, 256, 0, stream>>>(tTT, tDD, greg, l, Wt1, Wt2, Wt3);
            } else {
                split3_op<<<ogrid, 256, 0, stream>>>(tTT, tDD, greg, l, Wt1, Wt2, Wt3);
            }
            gemm_bf16x3<<<gg, 256, 0, stream>>>(c1, c2, c3, Wt1, Wt2, Wt3, part, klen, S);
            combine3<0><<<agrid, 256, 0, stream>>>(part, S, (l == 0 ? x : state), x_b,
                                                   nullptr, d1, d2, d3, gam, gmu, greg, l);
            if (mid) split3_op<<<ogrid, 256, 0, stream>>>(Pelt, nullptr, greg, 0, Pe1, Pe2, Pe3);
            gemm_bf16x3<<<gg, 256, 0, stream>>>(d1, d2, d3, Pe1, Pe2, Pe3, part, klen, S);
            combine3<1><<<agrid, 256, 0, stream>>>(part, S, nullptr, nullptr,
                                                   nullptr, c1, c2, c3, gam, gmu, greg, l);
            if (mid) split3_op<<<ogrid, 256, 0, stream>>>(Peig, nullptr, greg, 0, Pg1, Pg2, Pg3);
            gemm_bf16x3<<<gg, 256, 0, stream>>>(c1, c2, c3, Pg1, Pg2, Pg3, part, klen, S);
            combine3<2><<<agrid, 256, 0, stream>>>(part, S, nullptr, nullptr,
                                                   (l == NLAYERS - 1 ? out : state),
                                                   d1, d2, d3, gam, gmu, greg, l);
            unsigned short* t;
            t = c1; c1 = d1; d1 = t;
            t = c2; c2 = d2; d2 = t;
            t = c3; c3 = d3; d3 = t;
        }
        return;
    }

    // ---------------- legacy R2 fallback (ws < 48 MB) ----------------
    char* wsb = (char*)d_ws;
    float* b0 = (float*)wsb;
    float* b1 = b0 + MN;
    float* b2 = b1 + MN;
    float* b3 = b2 + MN;
    const size_t base_bytes = 4 * MN * sizeof(float);
    double* partd = (double*)(wsb + base_bytes);
    int S = 0;
    if (ws_size >= base_bytes + 2 * MN * sizeof(double)) S = 2;
    else if (ws_size >= base_bytes + 1 * MN * sizeof(double)) S = 1;
    if (S == 0) return;
    const int klen = KDIM / S;
    dim3 gg(NDIM / BN, MDIM / BM, S);
    dim3 cg((unsigned)(MN / 4 / 256));
    const float* cur = x;
    float* bx = b0; float* bu = b1; float* bn = b2; float* bo = b3;
    for (int l = 0; l < NLAYERS; ++l) {
        gemm_nt_splitk<true><<<gg, 256, 0, stream>>>(cur, tTT, tDD, partd, greg, l, klen);
        combine_ep<0><<<cg, 256, 0, stream>>>(partd, S, cur, x_b, bx, gam, gmu, greg, l);
        gemm_nt_splitk<false><<<gg, 256, 0, stream>>>(bx, Pelt, nullptr, partd, greg, l, klen);
        combine_ep<1><<<cg, 256, 0, stream>>>(partd, S, nullptr, nullptr, bu, gam, gmu, greg, l);
        gemm_nt_splitk<false><<<gg, 256, 0, stream>>>(bu, Peig, nullptr, partd, greg, l, klen);
        float* dst = (l == NLAYERS - 1) ? out : bn;
        combine_ep<2><<<cg, 256, 0, stream>>>(partd, S, nullptr, nullptr, dst, gam, gmu, greg, l);
        cur = bn;
        float* t = bn; bn = bo; bo = t;
    }
}